// Round 4
// baseline (895.846 us; speedup 1.0000x reference)
//
#include <hip/hip_runtime.h>
#include <math.h>

// ---------------------------------------------------------------------------
// Decoder step. Inputs: f32 (runtime-verified per input); outputs: f32.
// Internal GEMMs: bf16 MFMA with f32 accumulate.
// Shapes: B=256, L=128, V=4096, E_ENC=1024, D_DEC=1024, E_EMB=512
// Outputs (concat, f32): out (256x4096) | h_new (256x1024) | attn (256x128)
// ---------------------------------------------------------------------------

#define B_   256
#define L_   128
#define V_   4096
#define ENC_ 1024
#define DEC_ 1024
#define EMB_ 512
#define MB_  1048576

typedef __bf16 bf16;
typedef __bf16 bf16x8 __attribute__((ext_vector_type(8)));
typedef __bf16 bf16x4 __attribute__((ext_vector_type(4)));
typedef float  f32x4  __attribute__((ext_vector_type(4)));

__device__ __forceinline__ float sigmoidf_(float x) {
  return 1.0f / (1.0f + expf(-x));
}

// ---- dual-dtype loaders (flag: 1 = f32 storage, 0 = bf16 storage) ---------
__device__ __forceinline__ bf16x8 ld8d(const void* p, size_t e, int f32) {
  if (f32) {
    const float* f = (const float*)p + e;
    f32x4 a = *(const f32x4*)f;
    f32x4 b = *(const f32x4*)(f + 4);
    bf16x8 r;
    r[0] = (bf16)a[0]; r[1] = (bf16)a[1]; r[2] = (bf16)a[2]; r[3] = (bf16)a[3];
    r[4] = (bf16)b[0]; r[5] = (bf16)b[1]; r[6] = (bf16)b[2]; r[7] = (bf16)b[3];
    return r;
  }
  return *(const bf16x8*)((const bf16*)p + e);
}
__device__ __forceinline__ float ldsc(const void* p, size_t e, int f32) {
  return f32 ? ((const float*)p)[e] : (float)((const bf16*)p)[e];
}

// ---------------------------------------------------------------------------
// Per-input dtype detector (insurance). flags[i]=1 iff storage is f32.
// ---------------------------------------------------------------------------
struct PtrPack { const void* p[19]; int n[19]; };

__global__ __launch_bounds__(256) void detect_k(PtrPack pk, int* flags) {
  const int i = blockIdx.x;
  const unsigned short* h = (const unsigned short*)pk.p[i];
  int m = pk.n[i] / 2; if (m > 32768) m = 32768;
  __shared__ int c_big, c_zero;
  if (threadIdx.x == 0) { c_big = 0; c_zero = 0; }
  __syncthreads();
  int lb = 0, lz = 0;
  for (int j = threadIdx.x; j < m; j += 256) {
    unsigned short v = h[2 * j];
    int ex = (v >> 7) & 0xFF;
    if (ex >= 0xC0) lb++;           // |val| >= 2^65: impossible for real bf16
    if (v == 0) lz++;
  }
  atomicAdd(&c_big, lb);
  atomicAdd(&c_zero, lz);
  __syncthreads();
  if (threadIdx.x == 0)
    flags[i] = (c_big >= 1 || (m > 0 && 4 * c_zero >= 3 * m)) ? 1 : 0;
}

// ---------------------------------------------------------------------------
// Fused score GEMM: e_part[cb][b*128+l] = sum_{d in col-block cb}
//     tanh( enc[b,l,:]·W1[d,:] + u[b,d] ) * Vw[d]
// grid = (8, 256); block = 256 (4 waves).
// ---------------------------------------------------------------------------
__global__ __launch_bounds__(256) void score_gemm(
    const void* __restrict__ A,    // enc_output flat (32768 x 1024)
    const void* __restrict__ Bw,   // W1_w (1024 x 1024)
    const float* __restrict__ u,   // (256 x 1024) fp32 internal
    const void* __restrict__ Vw,   // (1024)
    float* __restrict__ e_part,    // (8 x 32768) fp32
    const int* __restrict__ flags)
{
  const int K = 1024;
  const int fA = flags[2], fB = flags[3], fV = flags[7];
  __shared__ __align__(16) bf16 As[128 * 64];
  __shared__ __align__(16) bf16 Bs[128 * 64];
  __shared__ float s_part[2][128];

  const int t    = threadIdx.x;
  const int lane = t & 63;
  const int w    = t >> 6;
  const int wm   = w >> 1;
  const int wn   = w & 1;
  const int q    = lane >> 4;
  const int c16  = lane & 15;

  const int cb   = blockIdx.x;
  const int row0 = blockIdx.y * 128;
  const int col0 = cb * 128;

  f32x4 acc[4][4] = {};

  for (int k0 = 0; k0 < K; k0 += 64) {
    bf16x8 va[4], vb[4];
#pragma unroll
    for (int ro = 0; ro < 4; ro++) {
      int eo = ro * 2048 + t * 8;
      int r  = eo >> 6;
      int c  = eo & 63;
      va[ro] = ld8d(A,  (size_t)(row0 + r) * K + (k0 + c), fA);
      vb[ro] = ld8d(Bw, (size_t)(col0 + r) * K + (k0 + c), fB);
    }
#pragma unroll
    for (int ro = 0; ro < 4; ro++) {
      int eo = ro * 2048 + t * 8;
      *(bf16x8*)&As[eo] = va[ro];
      *(bf16x8*)&Bs[eo] = vb[ro];
    }
    __syncthreads();
#pragma unroll
    for (int kk = 0; kk < 64; kk += 32) {
      bf16x8 af[4], bfr[4];
#pragma unroll
      for (int i = 0; i < 4; i++)
        af[i] = *(const bf16x8*)&As[(wm * 64 + i * 16 + c16) * 64 + kk + q * 8];
#pragma unroll
      for (int j = 0; j < 4; j++)
        bfr[j] = *(const bf16x8*)&Bs[(wn * 64 + j * 16 + c16) * 64 + kk + q * 8];
#pragma unroll
      for (int i = 0; i < 4; i++)
#pragma unroll
        for (int j = 0; j < 4; j++)
          acc[i][j] = __builtin_amdgcn_mfma_f32_16x16x32_bf16(af[i], bfr[j], acc[i][j], 0, 0, 0);
    }
    __syncthreads();
  }

  const int b = blockIdx.y;
  float rowsum[4][4] = {};
#pragma unroll
  for (int i = 0; i < 4; i++) {
#pragma unroll
    for (int j = 0; j < 4; j++) {
      int gc   = col0 + wn * 64 + j * 16 + c16;
      float uc = u[b * 1024 + gc];
      float vw = ldsc(Vw, gc, fV);
#pragma unroll
      for (int r = 0; r < 4; r++)
        rowsum[i][r] += tanhf(acc[i][j][r] + uc) * vw;
    }
  }
#pragma unroll
  for (int i = 0; i < 4; i++) {
#pragma unroll
    for (int r = 0; r < 4; r++) {
      float v = rowsum[i][r];
      v += __shfl_xor(v, 1);
      v += __shfl_xor(v, 2);
      v += __shfl_xor(v, 4);
      v += __shfl_xor(v, 8);
      if (c16 == 0) s_part[wn][wm * 64 + i * 16 + q * 4 + r] = v;
    }
  }
  __syncthreads();
  if (t < 128)
    e_part[(size_t)cb * 32768 + row0 + t] = s_part[0][t] + s_part[1][t];
}

// ---------------------------------------------------------------------------
// Skinny GEMM: C(MxN) = act( A @ Bw^T + b1 [+ b2] ). 64x64 tile, BK=64.
// iA/iB/ib1/ib2: flag index, or -1 => internal bf16; ib2 -1 => no b2.
// OUTF32: 1 => C is float*, else bf16*.
// ---------------------------------------------------------------------------
template <int ACT, int OUTF32>
__global__ __launch_bounds__(256) void gemm_sk(
    const void* __restrict__ A, const void* __restrict__ Bw,
    const void* __restrict__ b1, const void* __restrict__ b2,
    void* __restrict__ C, int K, int out_ld,
    const int* __restrict__ flags, int iA, int iB, int ib1, int ib2)
{
  const int fA  = (iA  >= 0) ? flags[iA]  : 0;
  const int fB  = (iB  >= 0) ? flags[iB]  : 0;
  const int fb1 = (ib1 >= 0) ? flags[ib1] : 0;
  const int fb2 = (ib2 >= 0) ? flags[ib2] : 0;

  __shared__ __align__(16) bf16 As[64 * 64];
  __shared__ __align__(16) bf16 Bs[64 * 64];

  const int t    = threadIdx.x;
  const int lane = t & 63;
  const int w    = t >> 6;
  const int q    = lane >> 4;
  const int c16  = lane & 15;
  const int row0 = blockIdx.y * 64;
  const int col0 = blockIdx.x * 64;

  f32x4 acc[4] = {};

  for (int k0 = 0; k0 < K; k0 += 64) {
    bf16x8 va[2], vb[2];
#pragma unroll
    for (int ro = 0; ro < 2; ro++) {
      int eo = ro * 2048 + t * 8;
      int r  = eo >> 6;
      int c  = eo & 63;
      va[ro] = ld8d(A,  (size_t)(row0 + r) * K + (k0 + c), fA);
      vb[ro] = ld8d(Bw, (size_t)(col0 + r) * K + (k0 + c), fB);
    }
#pragma unroll
    for (int ro = 0; ro < 2; ro++) {
      int eo = ro * 2048 + t * 8;
      *(bf16x8*)&As[eo] = va[ro];
      *(bf16x8*)&Bs[eo] = vb[ro];
    }
    __syncthreads();
#pragma unroll
    for (int kk = 0; kk < 64; kk += 32) {
      bf16x8 bfr = *(const bf16x8*)&Bs[(w * 16 + c16) * 64 + kk + q * 8];
#pragma unroll
      for (int i = 0; i < 4; i++) {
        bf16x8 af = *(const bf16x8*)&As[(i * 16 + c16) * 64 + kk + q * 8];
        acc[i] = __builtin_amdgcn_mfma_f32_16x16x32_bf16(af, bfr, acc[i], 0, 0, 0);
      }
    }
    __syncthreads();
  }

  const int gc = col0 + w * 16 + c16;
  float bias = ldsc(b1, gc, fb1) + (ib2 >= 0 ? ldsc(b2, gc, fb2) : 0.0f);
#pragma unroll
  for (int i = 0; i < 4; i++) {
    int gr0 = row0 + i * 16 + q * 4;
#pragma unroll
    for (int r = 0; r < 4; r++) {
      float v = acc[i][r] + bias;
      if (ACT == 1) v = tanhf(v);
      size_t off = (size_t)(gr0 + r) * out_ld + gc;
      if (OUTF32) ((float*)C)[off] = v;
      else        ((bf16*)C)[off] = (bf16)v;
    }
  }
}

// ---------------------------------------------------------------------------
// Sum partials + softmax over L + context. grid = 256 (one block per b).
// ---------------------------------------------------------------------------
__global__ __launch_bounds__(256) void softmax_ctx(
    const float* __restrict__ e_part, // (8, 32768)
    const void* __restrict__ enc,     // (256,128,1024)
    float* __restrict__ attn_out,     // -> d_out section 3 (f32)
    bf16* __restrict__ rnn_in,        // (256,1536) internal, ctx -> cols [0,1024)
    const int* __restrict__ flags)
{
  const int b  = blockIdx.x;
  const int t  = threadIdx.x;
  const int fE = flags[2];
  __shared__ float se[128];

  if (t < 128) {
    float s = 0.0f;
#pragma unroll
    for (int cb = 0; cb < 8; cb++) s += e_part[(size_t)cb * 32768 + b * 128 + t];
    se[t] = s;
  }
  __syncthreads();

  float m = -1e30f;
  for (int l = 0; l < 128; l++) m = fmaxf(m, se[l]);
  float sum = 0.0f;
  for (int l = 0; l < 128; l++) sum += expf(se[l] - m);
  float inv = 1.0f / sum;
  __syncthreads();
  if (t < 128) {
    float p = expf(se[t] - m) * inv;
    attn_out[b * 128 + t] = p;
    se[t] = p;
  }
  __syncthreads();

  float a0 = 0, a1 = 0, a2 = 0, a3 = 0;
  const size_t base = (size_t)b * L_ * ENC_ + t * 4;
  if (fE) {
    const float* ep = (const float*)enc + base;
    for (int l = 0; l < 128; l++) {
      float p = se[l];
      f32x4 v = *(const f32x4*)(ep + (size_t)l * ENC_);
      a0 += p * v[0]; a1 += p * v[1]; a2 += p * v[2]; a3 += p * v[3];
    }
  } else {
    const bf16* ep = (const bf16*)enc + base;
    for (int l = 0; l < 128; l++) {
      float p = se[l];
      bf16x4 v = *(const bf16x4*)(ep + (size_t)l * ENC_);
      a0 += p * (float)v[0]; a1 += p * (float)v[1];
      a2 += p * (float)v[2]; a3 += p * (float)v[3];
    }
  }
  bf16x4 o;
  o[0] = (bf16)a0; o[1] = (bf16)a1; o[2] = (bf16)a2; o[3] = (bf16)a3;
  *(bf16x4*)(rnn_in + (size_t)b * 1536 + t * 4) = o;
}

// ---------------------------------------------------------------------------
// GRU gates. 262144 threads.
// ---------------------------------------------------------------------------
__global__ __launch_bounds__(256) void gru_gate(
    const bf16* __restrict__ gi,    // (256,3072) internal
    const bf16* __restrict__ gh,    // (256,3072) internal
    const void* __restrict__ h0,    // (256,1024) external
    float* __restrict__ hnew_out,   // -> d_out section 2 (f32)
    bf16* __restrict__ hnew_i,      // internal bf16 copy
    const int* __restrict__ flags)
{
  int idx = blockIdx.x * 256 + threadIdx.x;
  int b = idx >> 10, d = idx & 1023;
  const bf16* gib = gi + b * 3072;
  const bf16* ghb = gh + b * 3072;
  float ir = (float)gib[d], iz = (float)gib[1024 + d], in = (float)gib[2048 + d];
  float hr = (float)ghb[d], hz = (float)ghb[1024 + d], hn = (float)ghb[2048 + d];
  float r = sigmoidf_(ir + hr);
  float z = sigmoidf_(iz + hz);
  float n = tanhf(in + r * hn);
  float h = (1.0f - z) * n + z * ldsc(h0, idx, flags[1]);
  hnew_out[idx] = h;
  hnew_i[idx]   = (bf16)h;
}

// ---------------------------------------------------------------------------
extern "C" void kernel_launch(void* const* d_in, const int* in_sizes, int n_in,
                              void* d_out, int out_size, void* d_ws, size_t ws_size,
                              hipStream_t stream) {
  float* out_main = (float*)d_out;                      // (256,4096) f32
  float* out_h    = out_main + (size_t)B_ * V_;         // (256,1024) f32
  float* out_attn = out_h + (size_t)B_ * DEC_;          // (256,128)  f32

  // workspace carve (total ~5.25 MB; gi overlays dead u+e_part region)
  char*  ws     = (char*)d_ws;
  float* u      = (float*)(ws);                  // [0.0, 1.0) MB f32, live 1-4
  float* e_part = (float*)(ws + 1 * MB_);        // [1.0, 2.0) MB f32, live 4-5
  bf16*  gi     = (bf16*) (ws);                  // [0.0, 1.5) MB bf16, live 6-7 (overlay)
  bf16*  gh     = (bf16*) (ws + 2 * MB_);        // [2.0, 3.5) MB bf16, live 2-7
  bf16*  rnn_in = (bf16*) (ws + 3 * MB_ + MB_ / 2);   // [3.5, 4.25) MB, live 3-6
  bf16*  tbuf   = (bf16*) (ws + 4 * MB_ + MB_ / 4);   // [4.25, 4.5) MB, live 8-9
  bf16*  hnew_i = (bf16*) (ws + 4 * MB_ + MB_ / 2);   // [4.5, 5.0) MB, live 7-8
  int*   flags  = (int*)  (ws + 5 * MB_);             // [5.0 MB, +76)

  // 0. per-input dtype detection
  PtrPack pk;
  for (int i = 0; i < 19 && i < n_in; i++) { pk.p[i] = d_in[i]; pk.n[i] = in_sizes[i]; }
  detect_k<<<19, 256, 0, stream>>>(pk, flags);

  const void* x      = d_in[0];
  const void* hidden = d_in[1];
  const void* enc    = d_in[2];

  // 1. u = h0 @ W2^T + W1_b + W2_b          (256x1024 f32, K=1024)
  gemm_sk<0, 1><<<dim3(DEC_ / 64, B_ / 64), 256, 0, stream>>>(
      hidden, d_in[5], d_in[4], d_in[6], u, 1024, 1024, flags, 1, 5, 4, 6);

  // 2. gh = h0 @ gru_wh^T + gru_bh          (256x3072 bf16, K=1024)
  gemm_sk<0, 0><<<dim3(3072 / 64, B_ / 64), 256, 0, stream>>>(
      hidden, d_in[12], d_in[14], nullptr, gh, 1024, 3072, flags, 1, 12, 14, -1);

  // 3. x_emb = x @ o2e_w^T + o2e_b -> rnn_in[:,1024:1536]   (256x512, K=4096)
  gemm_sk<0, 0><<<dim3(EMB_ / 64, B_ / 64), 256, 0, stream>>>(
      x, d_in[9], d_in[10], nullptr, rnn_in + 1024, 4096, 1536, flags, 0, 9, 10, -1);

  // 4. fused score GEMM -> e_part
  score_gemm<<<dim3(DEC_ / 128, (B_ * L_) / 128), 256, 0, stream>>>(
      enc, d_in[3], u, d_in[7], e_part, flags);

  // 5. partial-sum + softmax + context
  softmax_ctx<<<B_, 256, 0, stream>>>(e_part, enc, out_attn, rnn_in, flags);

  // 6. gi = rnn_in @ gru_wi^T + gru_bi      (256x3072 bf16, K=1536)
  gemm_sk<0, 0><<<dim3(3072 / 64, B_ / 64), 256, 0, stream>>>(
      rnn_in, d_in[11], d_in[13], nullptr, gi, 1536, 3072, flags, -1, 11, 13, -1);

  // 7. GRU gates -> h_new (f32 out + bf16 internal)
  gru_gate<<<(B_ * DEC_) / 256, 256, 0, stream>>>(gi, gh, hidden, out_h, hnew_i, flags);

  // 8. t = tanh(h_new @ fc1_w^T + fc1_b)    (256x512 bf16, K=1024)
  gemm_sk<1, 0><<<dim3(EMB_ / 64, B_ / 64), 256, 0, stream>>>(
      hnew_i, d_in[15], d_in[16], nullptr, tbuf, 1024, 512, flags, -1, 15, 16, -1);

  // 9. out = t @ fc2_w^T + fc2_b            (256x4096 f32, K=512)
  gemm_sk<0, 1><<<dim3(V_ / 64, B_ / 64), 256, 0, stream>>>(
      tbuf, d_in[17], d_in[18], nullptr, out_main, 512, 4096, flags, -1, 17, 18, -1);
}

// Round 5
// 494.683 us; speedup vs baseline: 1.8110x; 1.8110x over previous
//
#include <hip/hip_runtime.h>
#include <math.h>

// ---------------------------------------------------------------------------
// Decoder step. Inputs f32 (runtime-verified), outputs f32.
// Fast path (ws_size >= NEED): one-time bf16 conversion of all GEMM matrices,
// then global_load_lds(16B) staging with XOR-swizzled LDS (bank-conflict-free)
// in every GEMM. Fallback path = R4 (dual-dtype manual staging).
// Outputs (concat, f32): out (256x4096) | h_new (256x1024) | attn (256x128)
// ---------------------------------------------------------------------------

#define B_   256
#define L_   128
#define V_   4096
#define ENC_ 1024
#define DEC_ 1024
#define EMB_ 512
#define MB_  1048576

typedef __bf16 bf16;
typedef __bf16 bf16x8 __attribute__((ext_vector_type(8)));
typedef __bf16 bf16x4 __attribute__((ext_vector_type(4)));
typedef float  f32x4  __attribute__((ext_vector_type(4)));

__device__ __forceinline__ float sigmoidf_(float x) {
  return 1.0f / (1.0f + expf(-x));
}
__device__ __forceinline__ float fast_tanh(float x) {
  float e = __builtin_amdgcn_exp2f(x * 2.88539008177792681472f);
  return 1.0f - 2.0f * __builtin_amdgcn_rcpf(e + 1.0f);
}
__device__ __forceinline__ float fast_sigmoid(float x) {
  return __builtin_amdgcn_rcpf(1.0f + __builtin_amdgcn_exp2f(-1.44269504088896f * x));
}

// async 16B global->LDS copy (global_load_lds_dwordx4)
__device__ __forceinline__ void cp16(const void* g, void* l) {
  __builtin_amdgcn_global_load_lds(
      (const __attribute__((address_space(1))) void*)g,
      (__attribute__((address_space(3))) void*)l,
      16, 0, 0);
}

// ---- dual-dtype loaders (flag: 1 = f32 storage, 0 = bf16) [fallback+bias] --
__device__ __forceinline__ bf16x8 ld8d(const void* p, size_t e, int f32) {
  if (f32) {
    const float* f = (const float*)p + e;
    f32x4 a = *(const f32x4*)f;
    f32x4 b = *(const f32x4*)(f + 4);
    bf16x8 r;
    r[0] = (bf16)a[0]; r[1] = (bf16)a[1]; r[2] = (bf16)a[2]; r[3] = (bf16)a[3];
    r[4] = (bf16)b[0]; r[5] = (bf16)b[1]; r[6] = (bf16)b[2]; r[7] = (bf16)b[3];
    return r;
  }
  return *(const bf16x8*)((const bf16*)p + e);
}
__device__ __forceinline__ float ldsc(const void* p, size_t e, int f32) {
  return f32 ? ((const float*)p)[e] : (float)((const bf16*)p)[e];
}

// ---------------------------------------------------------------------------
// Per-input dtype detector. flags[i]=1 iff storage is f32.
// ---------------------------------------------------------------------------
struct PtrPack { const void* p[19]; int n[19]; };

__global__ __launch_bounds__(256) void detect_k(PtrPack pk, int* flags) {
  const int i = blockIdx.x;
  const unsigned short* h = (const unsigned short*)pk.p[i];
  int m = pk.n[i] / 2; if (m > 32768) m = 32768;
  __shared__ int c_big, c_zero;
  if (threadIdx.x == 0) { c_big = 0; c_zero = 0; }
  __syncthreads();
  int lb = 0, lz = 0;
  for (int j = threadIdx.x; j < m; j += 256) {
    unsigned short v = h[2 * j];
    int ex = (v >> 7) & 0xFF;
    if (ex >= 0xC0) lb++;
    if (v == 0) lz++;
  }
  atomicAdd(&c_big, lb);
  atomicAdd(&c_zero, lz);
  __syncthreads();
  if (threadIdx.x == 0)
    flags[i] = (c_big >= 1 || (m > 0 && 4 * c_zero >= 3 * m)) ? 1 : 0;
}

// ---------------------------------------------------------------------------
// Conversion pass: 10 segments f32->bf16 (or bf16 copy). 4096 elems/block.
// ---------------------------------------------------------------------------
struct CvtPack { const void* src[10]; bf16* dst[10]; int flagi[10]; int cum[11]; };

__global__ __launch_bounds__(256) void convert_k(CvtPack p, const int* flags) {
  int bid = blockIdx.x;
  int si = 0;
#pragma unroll
  for (int s = 0; s < 10; s++) if (bid >= p.cum[s + 1]) si = s + 1;
  const size_t base = (size_t)(bid - p.cum[si]) * 4096 + threadIdx.x * 16;
  bf16* d = p.dst[si] + base;
  if (flags[p.flagi[si]]) {
    const float* s = (const float*)p.src[si] + base;
    f32x4 v0 = *(const f32x4*)(s);
    f32x4 v1 = *(const f32x4*)(s + 4);
    f32x4 v2 = *(const f32x4*)(s + 8);
    f32x4 v3 = *(const f32x4*)(s + 12);
    bf16x8 r0, r1;
    r0[0] = (bf16)v0[0]; r0[1] = (bf16)v0[1]; r0[2] = (bf16)v0[2]; r0[3] = (bf16)v0[3];
    r0[4] = (bf16)v1[0]; r0[5] = (bf16)v1[1]; r0[6] = (bf16)v1[2]; r0[7] = (bf16)v1[3];
    r1[0] = (bf16)v2[0]; r1[1] = (bf16)v2[1]; r1[2] = (bf16)v2[2]; r1[3] = (bf16)v2[3];
    r1[4] = (bf16)v3[0]; r1[5] = (bf16)v3[1]; r1[6] = (bf16)v3[2]; r1[7] = (bf16)v3[3];
    *(bf16x8*)(d) = r0;
    *(bf16x8*)(d + 8) = r1;
  } else {
    const bf16* s = (const bf16*)p.src[si] + base;
    *(bf16x8*)(d) = *(const bf16x8*)(s);
    *(bf16x8*)(d + 8) = *(const bf16x8*)(s + 8);
  }
}

// ===========================================================================
// FAST-PATH KERNELS (bf16 inputs, global_load_lds, XOR-swizzled LDS)
// Swizzle: element (r,c) of a [R][64] tile lives at LDS offset
//   r*64 + ((c/8) ^ (r&7))*8 + (c%8).  Staging keeps LDS slots sequential
//   (global_load_lds constraint) and swizzles the GLOBAL column instead.
// ===========================================================================

// Fused score GEMM: e_part[cb][b*128+l] = sum_{d in cb} tanh(enc·W1 + u)*Vw
// grid = (8, 256); block = 256 (4 waves).
__global__ __launch_bounds__(256) void score_f(
    const bf16* __restrict__ A,    // enc_bf (32768 x 1024)
    const bf16* __restrict__ Bw,   // W1_bf (1024 x 1024)
    const bf16* __restrict__ u,    // (256 x 1024) bf16
    const void* __restrict__ Vw,   // (1024) external
    float* __restrict__ e_part,    // (8 x 32768)
    const int* __restrict__ flags)
{
  __shared__ __align__(16) bf16 As[128 * 64];
  __shared__ __align__(16) bf16 Bs[128 * 64];
  __shared__ float s_part[2][128];

  const int t    = threadIdx.x;
  const int lane = t & 63;
  const int w    = t >> 6;
  const int wm   = w >> 1;
  const int wn   = w & 1;
  const int q    = lane >> 4;
  const int c16  = lane & 15;
  const int sr   = t >> 3;      // staging row within chunk (0..31)
  const int lb   = t & 7;       // staging 16B-block within row

  const int cb   = blockIdx.x;
  const int row0 = blockIdx.y * 128;
  const int col0 = cb * 128;

  f32x4 acc[4][4] = {};

  for (int k0 = 0; k0 < 1024; k0 += 64) {
#pragma unroll
    for (int ch = 0; ch < 4; ch++) {
      int r    = ch * 32 + sr;
      int gcol = k0 + ((lb ^ (r & 7)) << 3);
      cp16(A  + (size_t)(row0 + r) * 1024 + gcol, &As[ch * 2048 + t * 8]);
      cp16(Bw + (size_t)(col0 + r) * 1024 + gcol, &Bs[ch * 2048 + t * 8]);
    }
    __syncthreads();   // drains vmcnt (global_load_lds) + barrier
#pragma unroll
    for (int kkb = 0; kkb < 8; kkb += 4) {   // kk = kkb*8 (0, 32)
      bf16x8 af[4], bfr[4];
#pragma unroll
      for (int i = 0; i < 4; i++) {
        int ra = wm * 64 + i * 16 + c16;
        af[i] = *(const bf16x8*)&As[ra * 64 + (((kkb + q) ^ (ra & 7)) << 3)];
      }
#pragma unroll
      for (int j = 0; j < 4; j++) {
        int rb = wn * 64 + j * 16 + c16;
        bfr[j] = *(const bf16x8*)&Bs[rb * 64 + (((kkb + q) ^ (rb & 7)) << 3)];
      }
#pragma unroll
      for (int i = 0; i < 4; i++)
#pragma unroll
        for (int j = 0; j < 4; j++)
          acc[i][j] = __builtin_amdgcn_mfma_f32_16x16x32_bf16(af[i], bfr[j], acc[i][j], 0, 0, 0);
    }
    __syncthreads();
  }

  const int b  = blockIdx.y;
  const int fV = flags[7];
  float rowsum[4][4] = {};
#pragma unroll
  for (int i = 0; i < 4; i++) {
#pragma unroll
    for (int j = 0; j < 4; j++) {
      int gc   = col0 + wn * 64 + j * 16 + c16;
      float uc = (float)u[b * 1024 + gc];
      float vw = ldsc(Vw, gc, fV);
#pragma unroll
      for (int r = 0; r < 4; r++)
        rowsum[i][r] += fast_tanh(acc[i][j][r] + uc) * vw;
    }
  }
#pragma unroll
  for (int i = 0; i < 4; i++) {
#pragma unroll
    for (int r = 0; r < 4; r++) {
      float v = rowsum[i][r];
      v += __shfl_xor(v, 1);
      v += __shfl_xor(v, 2);
      v += __shfl_xor(v, 4);
      v += __shfl_xor(v, 8);
      if (c16 == 0) s_part[wn][wm * 64 + i * 16 + q * 4 + r] = v;
    }
  }
  __syncthreads();
  if (t < 128)
    e_part[(size_t)cb * 32768 + row0 + t] = s_part[0][t] + s_part[1][t];
}

// Generic skinny GEMM (bf16): C = act(A @ B^T + bias). 64x64 tile, BK=64.
// grid = (N/64, M/64). Bias = b1[+b2] via dual-scalar loads (external f32).
template <int ACT, int OUTF32>
__global__ __launch_bounds__(256) void gemm_f(
    const bf16* __restrict__ A, const bf16* __restrict__ Bw,
    const void* __restrict__ b1, const void* __restrict__ b2,
    void* __restrict__ C, int K, int out_ld,
    const int* __restrict__ flags, int ib1, int ib2)
{
  __shared__ __align__(16) bf16 As[64 * 64];
  __shared__ __align__(16) bf16 Bs[64 * 64];

  const int t    = threadIdx.x;
  const int lane = t & 63;
  const int w    = t >> 6;
  const int q    = lane >> 4;
  const int c16  = lane & 15;
  const int sr   = t >> 3;
  const int lb   = t & 7;
  const int row0 = blockIdx.y * 64;
  const int col0 = blockIdx.x * 64;

  f32x4 acc[4] = {};

  for (int k0 = 0; k0 < K; k0 += 64) {
#pragma unroll
    for (int ch = 0; ch < 2; ch++) {
      int r    = ch * 32 + sr;
      int gcol = k0 + ((lb ^ (r & 7)) << 3);
      cp16(A  + (size_t)(row0 + r) * K + gcol, &As[ch * 2048 + t * 8]);
      cp16(Bw + (size_t)(col0 + r) * K + gcol, &Bs[ch * 2048 + t * 8]);
    }
    __syncthreads();
#pragma unroll
    for (int kkb = 0; kkb < 8; kkb += 4) {
      int rb = w * 16 + c16;
      bf16x8 bfr = *(const bf16x8*)&Bs[rb * 64 + (((kkb + q) ^ (rb & 7)) << 3)];
#pragma unroll
      for (int i = 0; i < 4; i++) {
        int ra = i * 16 + c16;
        bf16x8 af = *(const bf16x8*)&As[ra * 64 + (((kkb + q) ^ (ra & 7)) << 3)];
        acc[i] = __builtin_amdgcn_mfma_f32_16x16x32_bf16(af, bfr, acc[i], 0, 0, 0);
      }
    }
    __syncthreads();
  }

  const int gc = col0 + w * 16 + c16;
  float bias = ldsc(b1, gc, flags[ib1]) + (ib2 >= 0 ? ldsc(b2, gc, flags[ib2]) : 0.0f);
#pragma unroll
  for (int i = 0; i < 4; i++) {
    int gr0 = row0 + i * 16 + q * 4;
#pragma unroll
    for (int r = 0; r < 4; r++) {
      float v = acc[i][r] + bias;
      if (ACT == 1) v = fast_tanh(v);
      size_t off = (size_t)(gr0 + r) * out_ld + gc;
      if (OUTF32) ((float*)C)[off] = v;
      else        ((bf16*)C)[off] = (bf16)v;
    }
  }
}

// Fused u|gh GEMM from h0_bf: cols [0,1024) -> u_bf (W2, +W1_b+W2_b),
// cols [1024,4096) -> gh_bf (gru_wh, +gru_bh). K=1024. grid (64,4).
__global__ __launch_bounds__(256) void ugh_f(
    const bf16* __restrict__ A,    // h0_bf (256x1024)
    const bf16* __restrict__ W2b,  // W2_bf (1024x1024)
    const bf16* __restrict__ Whb,  // wh_bf (3072x1024)
    const void* __restrict__ W1_b, const void* __restrict__ W2_b,
    const void* __restrict__ gbh,
    bf16* __restrict__ u,          // (256x1024)
    bf16* __restrict__ gh,         // (256x3072)
    const int* __restrict__ flags)
{
  __shared__ __align__(16) bf16 As[64 * 64];
  __shared__ __align__(16) bf16 Bs[64 * 64];

  const int t    = threadIdx.x;
  const int lane = t & 63;
  const int w    = t >> 6;
  const int q    = lane >> 4;
  const int c16  = lane & 15;
  const int sr   = t >> 3;
  const int lb   = t & 7;
  const int row0 = blockIdx.y * 64;
  const int col0 = blockIdx.x * 64;
  const bool isU = (col0 < 1024);
  const bf16* Bw = isU ? (W2b + (size_t)col0 * 1024)
                       : (Whb + (size_t)(col0 - 1024) * 1024);

  f32x4 acc[4] = {};

  for (int k0 = 0; k0 < 1024; k0 += 64) {
#pragma unroll
    for (int ch = 0; ch < 2; ch++) {
      int r    = ch * 32 + sr;
      int gcol = k0 + ((lb ^ (r & 7)) << 3);
      cp16(A  + (size_t)(row0 + r) * 1024 + gcol, &As[ch * 2048 + t * 8]);
      cp16(Bw + (size_t)r * 1024 + gcol, &Bs[ch * 2048 + t * 8]);
    }
    __syncthreads();
#pragma unroll
    for (int kkb = 0; kkb < 8; kkb += 4) {
      int rb = w * 16 + c16;
      bf16x8 bfr = *(const bf16x8*)&Bs[rb * 64 + (((kkb + q) ^ (rb & 7)) << 3)];
#pragma unroll
      for (int i = 0; i < 4; i++) {
        int ra = i * 16 + c16;
        bf16x8 af = *(const bf16x8*)&As[ra * 64 + (((kkb + q) ^ (ra & 7)) << 3)];
        acc[i] = __builtin_amdgcn_mfma_f32_16x16x32_bf16(af, bfr, acc[i], 0, 0, 0);
      }
    }
    __syncthreads();
  }

  const int gc = col0 + w * 16 + c16;
  float bias;
  if (isU) bias = ldsc(W1_b, gc, flags[4]) + ldsc(W2_b, gc, flags[6]);
  else     bias = ldsc(gbh, gc - 1024, flags[14]);
#pragma unroll
  for (int i = 0; i < 4; i++) {
    int gr0 = row0 + i * 16 + q * 4;
#pragma unroll
    for (int r = 0; r < 4; r++) {
      float v = acc[i][r] + bias;
      if (isU) u[(size_t)(gr0 + r) * 1024 + gc] = (bf16)v;
      else     gh[(size_t)(gr0 + r) * 3072 + (gc - 1024)] = (bf16)v;
    }
  }
}

// x_emb split-K: xe4[z][256][512] = x_bf @ o2e_bf^T over K slab z*1024..+1024.
// grid (8, 4, 4).
__global__ __launch_bounds__(256) void xemb_f(
    const bf16* __restrict__ A,    // x_bf (256x4096)
    const bf16* __restrict__ Bw,   // o2e_bf (512x4096)
    float* __restrict__ xe4)       // (4,256,512)
{
  __shared__ __align__(16) bf16 As[64 * 64];
  __shared__ __align__(16) bf16 Bs[64 * 64];

  const int t    = threadIdx.x;
  const int lane = t & 63;
  const int w    = t >> 6;
  const int q    = lane >> 4;
  const int c16  = lane & 15;
  const int sr   = t >> 3;
  const int lb   = t & 7;
  const int row0 = blockIdx.y * 64;
  const int col0 = blockIdx.x * 64;
  const int z    = blockIdx.z;
  const int kbeg = z * 1024;

  f32x4 acc[4] = {};

  for (int k0 = kbeg; k0 < kbeg + 1024; k0 += 64) {
#pragma unroll
    for (int ch = 0; ch < 2; ch++) {
      int r    = ch * 32 + sr;
      int gcol = k0 + ((lb ^ (r & 7)) << 3);
      cp16(A  + (size_t)(row0 + r) * 4096 + gcol, &As[ch * 2048 + t * 8]);
      cp16(Bw + (size_t)(col0 + r) * 4096 + gcol, &Bs[ch * 2048 + t * 8]);
    }
    __syncthreads();
#pragma unroll
    for (int kkb = 0; kkb < 8; kkb += 4) {
      int rb = w * 16 + c16;
      bf16x8 bfr = *(const bf16x8*)&Bs[rb * 64 + (((kkb + q) ^ (rb & 7)) << 3)];
#pragma unroll
      for (int i = 0; i < 4; i++) {
        int ra = i * 16 + c16;
        bf16x8 af = *(const bf16x8*)&As[ra * 64 + (((kkb + q) ^ (ra & 7)) << 3)];
        acc[i] = __builtin_amdgcn_mfma_f32_16x16x32_bf16(af, bfr, acc[i], 0, 0, 0);
      }
    }
    __syncthreads();
  }

  const int gc = col0 + w * 16 + c16;
  float* out = xe4 + (size_t)z * 131072;
#pragma unroll
  for (int i = 0; i < 4; i++) {
    int gr0 = row0 + i * 16 + q * 4;
#pragma unroll
    for (int r = 0; r < 4; r++)
      out[(size_t)(gr0 + r) * 512 + gc] = acc[i][r];
  }
}

// softmax + context + x_emb pack. grid 256 (one per b).
__global__ __launch_bounds__(256) void softmax_f(
    const float* __restrict__ e_part, // (8, 32768)
    const bf16* __restrict__ enc,     // enc_bf (256,128,1024)
    const float* __restrict__ xe4,    // (4,256,512)
    const void* __restrict__ o2eb,    // (512) external
    float* __restrict__ attn_out,     // -> d_out section 3
    bf16* __restrict__ rnn_in,        // (256,1536)
    const int* __restrict__ flags)
{
  const int b = blockIdx.x;
  const int t = threadIdx.x;
  __shared__ float se[128];

  if (t < 128) {
    float s = 0.0f;
#pragma unroll
    for (int cb = 0; cb < 8; cb++) s += e_part[(size_t)cb * 32768 + b * 128 + t];
    se[t] = s;
  }
  __syncthreads();

  float m = -1e30f;
  for (int l = 0; l < 128; l++) m = fmaxf(m, se[l]);
  float sum = 0.0f;
  for (int l = 0; l < 128; l++) sum += expf(se[l] - m);
  float inv = 1.0f / sum;
  __syncthreads();
  if (t < 128) {
    float p = expf(se[t] - m) * inv;
    attn_out[b * 128 + t] = p;
    se[t] = p;
  }
  __syncthreads();

  // context: thread t handles 4 contiguous k of 1024
  float a0 = 0, a1 = 0, a2 = 0, a3 = 0;
  const bf16* ep = enc + (size_t)b * L_ * ENC_ + t * 4;
  for (int l = 0; l < 128; l++) {
    float p = se[l];
    bf16x4 v = *(const bf16x4*)(ep + (size_t)l * ENC_);
    a0 += p * (float)v[0]; a1 += p * (float)v[1];
    a2 += p * (float)v[2]; a3 += p * (float)v[3];
  }
  bf16x4 o;
  o[0] = (bf16)a0; o[1] = (bf16)a1; o[2] = (bf16)a2; o[3] = (bf16)a3;
  *(bf16x4*)(rnn_in + (size_t)b * 1536 + t * 4) = o;

  // pack x_emb: rnn_in[b][1024+j] = sum_z xe4[z][b][j] + o2e_b[j]
  const int fB = flags[10];
#pragma unroll
  for (int jj = 0; jj < 2; jj++) {
    int j = jj * 256 + t;
    float v = ldsc(o2eb, j, fB);
#pragma unroll
    for (int z = 0; z < 4; z++) v += xe4[(size_t)z * 131072 + b * 512 + j];
    rnn_in[(size_t)b * 1536 + 1024 + j] = (bf16)v;
  }
}

// GRU gates (fast): gi/gh bf16 internal, h0 external. 262144 threads.
__global__ __launch_bounds__(256) void gru_f(
    const bf16* __restrict__ gi, const bf16* __restrict__ gh,
    const void* __restrict__ h0,
    float* __restrict__ hnew_out, bf16* __restrict__ hnew_i,
    const int* __restrict__ flags)
{
  int idx = blockIdx.x * 256 + threadIdx.x;
  int b = idx >> 10, d = idx & 1023;
  const bf16* gib = gi + b * 3072;
  const bf16* ghb = gh + b * 3072;
  float ir = (float)gib[d], iz = (float)gib[1024 + d], in = (float)gib[2048 + d];
  float hr = (float)ghb[d], hz = (float)ghb[1024 + d], hn = (float)ghb[2048 + d];
  float r = fast_sigmoid(ir + hr);
  float z = fast_sigmoid(iz + hz);
  float n = fast_tanh(in + r * hn);
  float h = (1.0f - z) * n + z * ldsc(h0, idx, flags[1]);
  hnew_out[idx] = h;
  hnew_i[idx]   = (bf16)h;
}

// ===========================================================================
// FALLBACK KERNELS (R4, dual-dtype manual staging) — used if ws too small.
// ===========================================================================
__global__ __launch_bounds__(256) void score_gemm(
    const void* __restrict__ A, const void* __restrict__ Bw,
    const float* __restrict__ u, const void* __restrict__ Vw,
    float* __restrict__ e_part, const int* __restrict__ flags)
{
  const int K = 1024;
  const int fA = flags[2], fB = flags[3], fV = flags[7];
  __shared__ __align__(16) bf16 As[128 * 64];
  __shared__ __align__(16) bf16 Bs[128 * 64];
  __shared__ float s_part[2][128];

  const int t = threadIdx.x, lane = t & 63, w = t >> 6;
  const int wm = w >> 1, wn = w & 1, q = lane >> 4, c16 = lane & 15;
  const int cb = blockIdx.x, row0 = blockIdx.y * 128, col0 = cb * 128;

  f32x4 acc[4][4] = {};
  for (int k0 = 0; k0 < K; k0 += 64) {
    bf16x8 va[4], vb[4];
#pragma unroll
    for (int ro = 0; ro < 4; ro++) {
      int eo = ro * 2048 + t * 8, r = eo >> 6, c = eo & 63;
      va[ro] = ld8d(A,  (size_t)(row0 + r) * K + (k0 + c), fA);
      vb[ro] = ld8d(Bw, (size_t)(col0 + r) * K + (k0 + c), fB);
    }
#pragma unroll
    for (int ro = 0; ro < 4; ro++) {
      int eo = ro * 2048 + t * 8;
      *(bf16x8*)&As[eo] = va[ro];
      *(bf16x8*)&Bs[eo] = vb[ro];
    }
    __syncthreads();
#pragma unroll
    for (int kk = 0; kk < 64; kk += 32) {
      bf16x8 af[4], bfr[4];
#pragma unroll
      for (int i = 0; i < 4; i++)
        af[i] = *(const bf16x8*)&As[(wm * 64 + i * 16 + c16) * 64 + kk + q * 8];
#pragma unroll
      for (int j = 0; j < 4; j++)
        bfr[j] = *(const bf16x8*)&Bs[(wn * 64 + j * 16 + c16) * 64 + kk + q * 8];
#pragma unroll
      for (int i = 0; i < 4; i++)
#pragma unroll
        for (int j = 0; j < 4; j++)
          acc[i][j] = __builtin_amdgcn_mfma_f32_16x16x32_bf16(af[i], bfr[j], acc[i][j], 0, 0, 0);
    }
    __syncthreads();
  }
  const int b = blockIdx.y;
  float rowsum[4][4] = {};
#pragma unroll
  for (int i = 0; i < 4; i++)
#pragma unroll
    for (int j = 0; j < 4; j++) {
      int gc = col0 + wn * 64 + j * 16 + c16;
      float uc = u[b * 1024 + gc];
      float vw = ldsc(Vw, gc, fV);
#pragma unroll
      for (int r = 0; r < 4; r++)
        rowsum[i][r] += tanhf(acc[i][j][r] + uc) * vw;
    }
#pragma unroll
  for (int i = 0; i < 4; i++)
#pragma unroll
    for (int r = 0; r < 4; r++) {
      float v = rowsum[i][r];
      v += __shfl_xor(v, 1); v += __shfl_xor(v, 2);
      v += __shfl_xor(v, 4); v += __shfl_xor(v, 8);
      if (c16 == 0) s_part[wn][wm * 64 + i * 16 + q * 4 + r] = v;
    }
  __syncthreads();
  if (t < 128)
    e_part[(size_t)cb * 32768 + row0 + t] = s_part[0][t] + s_part[1][t];
}

template <int ACT, int OUTF32>
__global__ __launch_bounds__(256) void gemm_sk(
    const void* __restrict__ A, const void* __restrict__ Bw,
    const void* __restrict__ b1, const void* __restrict__ b2,
    void* __restrict__ C, int K, int out_ld,
    const int* __restrict__ flags, int iA, int iB, int ib1, int ib2)
{
  const int fA = (iA >= 0) ? flags[iA] : 0;
  const int fB = (iB >= 0) ? flags[iB] : 0;
  const int fb1 = (ib1 >= 0) ? flags[ib1] : 0;
  const int fb2 = (ib2 >= 0) ? flags[ib2] : 0;
  __shared__ __align__(16) bf16 As[64 * 64];
  __shared__ __align__(16) bf16 Bs[64 * 64];
  const int t = threadIdx.x, lane = t & 63, w = t >> 6;
  const int q = lane >> 4, c16 = lane & 15;
  const int row0 = blockIdx.y * 64, col0 = blockIdx.x * 64;
  f32x4 acc[4] = {};
  for (int k0 = 0; k0 < K; k0 += 64) {
    bf16x8 va[2], vb[2];
#pragma unroll
    for (int ro = 0; ro < 2; ro++) {
      int eo = ro * 2048 + t * 8, r = eo >> 6, c = eo & 63;
      va[ro] = ld8d(A,  (size_t)(row0 + r) * K + (k0 + c), fA);
      vb[ro] = ld8d(Bw, (size_t)(col0 + r) * K + (k0 + c), fB);
    }
#pragma unroll
    for (int ro = 0; ro < 2; ro++) {
      int eo = ro * 2048 + t * 8;
      *(bf16x8*)&As[eo] = va[ro];
      *(bf16x8*)&Bs[eo] = vb[ro];
    }
    __syncthreads();
#pragma unroll
    for (int kk = 0; kk < 64; kk += 32) {
      bf16x8 bfr = *(const bf16x8*)&Bs[(w * 16 + c16) * 64 + kk + q * 8];
#pragma unroll
      for (int i = 0; i < 4; i++) {
        bf16x8 af = *(const bf16x8*)&As[(i * 16 + c16) * 64 + kk + q * 8];
        acc[i] = __builtin_amdgcn_mfma_f32_16x16x32_bf16(af, bfr, acc[i], 0, 0, 0);
      }
    }
    __syncthreads();
  }
  const int gc = col0 + w * 16 + c16;
  float bias = ldsc(b1, gc, fb1) + (ib2 >= 0 ? ldsc(b2, gc, fb2) : 0.0f);
#pragma unroll
  for (int i = 0; i < 4; i++) {
    int gr0 = row0 + i * 16 + q * 4;
#pragma unroll
    for (int r = 0; r < 4; r++) {
      float v = acc[i][r] + bias;
      if (ACT == 1) v = tanhf(v);
      size_t off = (size_t)(gr0 + r) * out_ld + gc;
      if (OUTF32) ((float*)C)[off] = v;
      else        ((bf16*)C)[off] = (bf16)v;
    }
  }
}

__global__ __launch_bounds__(256) void softmax_ctx(
    const float* __restrict__ e_part, const void* __restrict__ enc,
    float* __restrict__ attn_out, bf16* __restrict__ rnn_in,
    const int* __restrict__ flags)
{
  const int b = blockIdx.x, t = threadIdx.x;
  const int fE = flags[2];
  __shared__ float se[128];
  if (t < 128) {
    float s = 0.0f;
#pragma unroll
    for (int cb = 0; cb < 8; cb++) s += e_part[(size_t)cb * 32768 + b * 128 + t];
    se[t] = s;
  }
  __syncthreads();
  float m = -1e30f;
  for (int l = 0; l < 128; l++) m = fmaxf(m, se[l]);
  float sum = 0.0f;
  for (int l = 0; l < 128; l++) sum += expf(se[l] - m);
  float inv = 1.0f / sum;
  __syncthreads();
  if (t < 128) {
    float p = expf(se[t] - m) * inv;
    attn_out[b * 128 + t] = p;
    se[t] = p;
  }
  __syncthreads();
  float a0 = 0, a1 = 0, a2 = 0, a3 = 0;
  const size_t base = (size_t)b * L_ * ENC_ + t * 4;
  if (fE) {
    const float* ep = (const float*)enc + base;
    for (int l = 0; l < 128; l++) {
      float p = se[l];
      f32x4 v = *(const f32x4*)(ep + (size_t)l * ENC_);
      a0 += p * v[0]; a1 += p * v[1]; a2 += p * v[2]; a3 += p * v[3];
    }
  } else {
    const bf16* ep = (const bf16*)enc + base;
    for (int l = 0; l < 128; l++) {
      float p = se[l];
      bf16x4 v = *(const bf16x4*)(ep + (size_t)l * ENC_);
      a0 += p * (float)v[0]; a1 += p * (float)v[1];
      a2 += p * (float)v[2]; a3 += p * (float)v[3];
    }
  }
  bf16x4 o;
  o[0] = (bf16)a0; o[1] = (bf16)a1; o[2] = (bf16)a2; o[3] = (bf16)a3;
  *(bf16x4*)(rnn_in + (size_t)b * 1536 + t * 4) = o;
}

__global__ __launch_bounds__(256) void gru_gate(
    const bf16* __restrict__ gi, const bf16* __restrict__ gh,
    const void* __restrict__ h0, float* __restrict__ hnew_out,
    bf16* __restrict__ hnew_i, const int* __restrict__ flags)
{
  int idx = blockIdx.x * 256 + threadIdx.x;
  int b = idx >> 10, d = idx & 1023;
  const bf16* gib = gi + b * 3072;
  const bf16* ghb = gh + b * 3072;
  float ir = (float)gib[d], iz = (float)gib[1024 + d], in = (float)gib[2048 + d];
  float hr = (float)ghb[d], hz = (float)ghb[1024 + d], hn = (float)ghb[2048 + d];
  float r = sigmoidf_(ir + hr);
  float z = sigmoidf_(iz + hz);
  float n = tanhf(in + r * hn);
  float h = (1.0f - z) * n + z * ldsc(h0, idx, flags[1]);
  hnew_out[idx] = h;
  hnew_i[idx]   = (bf16)h;
}

// ---------------------------------------------------------------------------
extern "C" void kernel_launch(void* const* d_in, const int* in_sizes, int n_in,
                              void* d_out, int out_size, void* d_ws, size_t ws_size,
                              hipStream_t stream) {
  float* out_main = (float*)d_out;
  float* out_h    = out_main + (size_t)B_ * V_;
  float* out_attn = out_h + (size_t)B_ * DEC_;
  char*  ws       = (char*)d_ws;

  PtrPack pk;
  for (int i = 0; i < 19 && i < n_in; i++) { pk.p[i] = d_in[i]; pk.n[i] = in_sizes[i]; }

  // ---- fast-path ws layout (byte offsets) ----
  const size_t o_enc = 0,            o_W1 = 64 * (size_t)MB_, o_wi = 66 * (size_t)MB_;
  const size_t o_wh  = 75 * (size_t)MB_, o_W2 = 81 * (size_t)MB_, o_o2e = 83 * (size_t)MB_;
  const size_t o_fc1 = 87 * (size_t)MB_, o_fc2 = 88 * (size_t)MB_, o_x = 92 * (size_t)MB_;
  const size_t o_h0  = 94 * (size_t)MB_;
  const size_t o_u   = o_h0 + 524288, o_ep = 95 * (size_t)MB_, o_gh = 96 * (size_t)MB_;
  const size_t o_gi  = o_gh + 1572864, o_rnn = 99 * (size_t)MB_, o_tb = o_rnn + 786432;
  const size_t o_hn  = 100 * (size_t)MB_, o_xe = o_hn + 524288;
  const size_t o_fl  = o_xe + 2097152;
  const size_t NEED  = o_fl + 4096;

  if (ws_size >= NEED) {
    // =================== FAST PATH ===================
    bf16* enc_bf = (bf16*)(ws + o_enc);
    bf16* W1_bf  = (bf16*)(ws + o_W1);
    bf16* wi_bf  = (bf16*)(ws + o_wi);
    bf16* wh_bf  = (bf16*)(ws + o_wh);
    bf16* W2_bf  = (bf16*)(ws + o_W2);
    bf16* o2e_bf = (bf16*)(ws + o_o2e);
    bf16* fc1_bf = (bf16*)(ws + o_fc1);
    bf16* fc2_bf = (bf16*)(ws + o_fc2);
    bf16* x_bf   = (bf16*)(ws + o_x);
    bf16* h0_bf  = (bf16*)(ws + o_h0);
    bf16* u_bf   = (bf16*)(ws + o_u);
    float* e_part= (float*)(ws + o_ep);
    bf16* gh_bf  = (bf16*)(ws + o_gh);
    bf16* gi_bf  = (bf16*)(ws + o_gi);
    bf16* rnn_in = (bf16*)(ws + o_rnn);
    bf16* tbuf   = (bf16*)(ws + o_tb);
    bf16* hnew_bf= (bf16*)(ws + o_hn);
    float* xe4   = (float*)(ws + o_xe);
    int*  flags  = (int*)(ws + o_fl);

    detect_k<<<19, 256, 0, stream>>>(pk, flags);

    // conversion: 10 segments, 4096 elems/block
    CvtPack cp;
    const int  srcs[10] = {2, 3, 11, 12, 5, 9, 15, 17, 0, 1};
    bf16* dsts[10] = {enc_bf, W1_bf, wi_bf, wh_bf, W2_bf, o2e_bf, fc1_bf, fc2_bf, x_bf, h0_bf};
    const int nelem[10] = {33554432, 1048576, 4718592, 3145728, 1048576,
                           2097152, 524288, 2097152, 1048576, 262144};
    int cum = 0;
    for (int s = 0; s < 10; s++) {
      cp.src[s] = d_in[srcs[s]]; cp.dst[s] = dsts[s]; cp.flagi[s] = srcs[s];
      cp.cum[s] = cum; cum += nelem[s] / 4096;
    }
    cp.cum[10] = cum;
    convert_k<<<cum, 256, 0, stream>>>(cp, flags);

    // u|gh fused (N=4096, K=1024)
    ugh_f<<<dim3(64, 4), 256, 0, stream>>>(
        h0_bf, W2_bf, wh_bf, d_in[4], d_in[6], d_in[14], u_bf, gh_bf, flags);

    // x_emb split-K -> xe4
    xemb_f<<<dim3(8, 4, 4), 256, 0, stream>>>(x_bf, o2e_bf, xe4);

    // score
    score_f<<<dim3(8, 256), 256, 0, stream>>>(
        enc_bf, W1_bf, u_bf, d_in[7], e_part, flags);

    // softmax + context + xe pack
    softmax_f<<<B_, 256, 0, stream>>>(
        e_part, enc_bf, xe4, d_in[10], out_attn, rnn_in, flags);

    // gi = rnn_in @ wi^T + gru_bi (N=3072, K=1536)
    gemm_f<0, 0><<<dim3(48, 4), 256, 0, stream>>>(
        rnn_in, wi_bf, d_in[13], nullptr, gi_bf, 1536, 3072, flags, 13, -1);

    // GRU gates
    gru_f<<<(B_ * DEC_) / 256, 256, 0, stream>>>(
        gi_bf, gh_bf, d_in[1], out_h, hnew_bf, flags);

    // fc1 (tanh) -> tbuf (N=512, K=1024)
    gemm_f<1, 0><<<dim3(8, 4), 256, 0, stream>>>(
        hnew_bf, fc1_bf, d_in[16], nullptr, tbuf, 1024, 512, flags, 16, -1);

    // out = tbuf @ fc2^T + fc2_b (N=4096, K=512, f32 out)
    gemm_f<0, 1><<<dim3(64, 4), 256, 0, stream>>>(
        tbuf, fc2_bf, d_in[18], nullptr, out_main, 512, 4096, flags, 18, -1);
  } else {
    // =================== FALLBACK (R4) ===================
    float* u      = (float*)(ws);
    float* e_part = (float*)(ws + 1 * MB_);
    bf16*  gi     = (bf16*) (ws);
    bf16*  gh     = (bf16*) (ws + 2 * MB_);
    bf16*  rnn_in = (bf16*) (ws + 3 * MB_ + MB_ / 2);
    bf16*  tbuf   = (bf16*) (ws + 4 * MB_ + MB_ / 4);
    bf16*  hnew_i = (bf16*) (ws + 4 * MB_ + MB_ / 2);
    int*   flags  = (int*)  (ws + 5 * MB_);

    detect_k<<<19, 256, 0, stream>>>(pk, flags);

    gemm_sk<0, 1><<<dim3(DEC_ / 64, B_ / 64), 256, 0, stream>>>(
        d_in[1], d_in[5], d_in[4], d_in[6], u, 1024, 1024, flags, 1, 5, 4, 6);
    gemm_sk<0, 0><<<dim3(3072 / 64, B_ / 64), 256, 0, stream>>>(
        d_in[1], d_in[12], d_in[14], nullptr, gh, 1024, 3072, flags, 1, 12, 14, -1);
    gemm_sk<0, 0><<<dim3(EMB_ / 64, B_ / 64), 256, 0, stream>>>(
        d_in[0], d_in[9], d_in[10], nullptr, rnn_in + 1024, 4096, 1536, flags, 0, 9, 10, -1);
    score_gemm<<<dim3(DEC_ / 128, (B_ * L_) / 128), 256, 0, stream>>>(
        d_in[2], d_in[3], u, d_in[7], e_part, flags);
    softmax_ctx<<<B_, 256, 0, stream>>>(e_part, d_in[2], out_attn, rnn_in, flags);
    gemm_sk<0, 0><<<dim3(3072 / 64, B_ / 64), 256, 0, stream>>>(
        rnn_in, d_in[11], d_in[13], nullptr, gi, 1536, 3072, flags, -1, 11, 13, -1);
    gru_gate<<<(B_ * DEC_) / 256, 256, 0, stream>>>(gi, gh, d_in[1], out_h, hnew_i, flags);
    gemm_sk<1, 0><<<dim3(EMB_ / 64, B_ / 64), 256, 0, stream>>>(
        hnew_i, d_in[15], d_in[16], nullptr, tbuf, 1024, 512, flags, -1, 15, 16, -1);
    gemm_sk<0, 1><<<dim3(V_ / 64, B_ / 64), 256, 0, stream>>>(
        tbuf, d_in[17], d_in[18], nullptr, out_main, 512, 4096, flags, -1, 17, 18, -1);
  }
}

// Round 6
// 432.980 us; speedup vs baseline: 2.0690x; 1.1425x over previous
//
#include <hip/hip_runtime.h>
#include <math.h>

// ---------------------------------------------------------------------------
// Decoder step. Inputs all f32 (measured by on-device detector in R2/R4 —
// now hard-coded); outputs f32. bf16 MFMA GEMMs with f32 accumulate.
// Launch graph (7 kernels):
//   setup_k  : ugh-GEMM + xemb-GEMM (f32-staged, run first) overlapped with
//              f32->bf16 conversion of enc/W1/wi/fc1/fc2 (one launch)
//   score_f2 : fused score GEMM, 2 col-blocks/block (halves enc HBM passes)
//   softmax_f: partial-sum + softmax + context + x_emb pack
//   gemm_f   : gi GEMM ; gru_f ; gemm_f fc1(tanh) ; gemm_f fc2 (f32 out)
// Outputs (concat, f32): out (256x4096) | h_new (256x1024) | attn (256x128)
// ---------------------------------------------------------------------------

#define B_   256
#define L_   128
#define V_   4096
#define ENC_ 1024
#define DEC_ 1024
#define EMB_ 512
#define MB_  1048576ull

typedef __bf16 bf16;
typedef __bf16 bf16x8 __attribute__((ext_vector_type(8)));
typedef __bf16 bf16x4 __attribute__((ext_vector_type(4)));
typedef float  f32x4  __attribute__((ext_vector_type(4)));

__device__ __forceinline__ float fast_tanh(float x) {
  float e = __builtin_amdgcn_exp2f(x * 2.88539008177792681472f);
  return 1.0f - 2.0f * __builtin_amdgcn_rcpf(e + 1.0f);
}
__device__ __forceinline__ float fast_sigmoid(float x) {
  return __builtin_amdgcn_rcpf(1.0f + __builtin_amdgcn_exp2f(-1.44269504088896f * x));
}

// async 16B global->LDS copy
__device__ __forceinline__ void cp16(const void* g, void* l) {
  __builtin_amdgcn_global_load_lds(
      (const __attribute__((address_space(1))) void*)g,
      (__attribute__((address_space(3))) void*)l,
      16, 0, 0);
}

// 8 f32 -> bf16x8
__device__ __forceinline__ bf16x8 ld8f(const float* f) {
  f32x4 a = *(const f32x4*)f;
  f32x4 b = *(const f32x4*)(f + 4);
  bf16x8 r;
  r[0] = (bf16)a[0]; r[1] = (bf16)a[1]; r[2] = (bf16)a[2]; r[3] = (bf16)a[3];
  r[4] = (bf16)b[0]; r[5] = (bf16)b[1]; r[6] = (bf16)b[2]; r[7] = (bf16)b[3];
  return r;
}

// ---------------------------------------------------------------------------
// LDS XOR swizzle (R5-verified, 0 bank conflicts):
// tile slot (r, lb) [lb = 16B block 0..7] holds global cols
// k0 + ((lb ^ (r&7))*8 .. +8). Fragment read for (row ra, k-quad kq):
// offset = ra*64 + ((kq ^ (ra&7))<<3).
// ---------------------------------------------------------------------------

// 64x64-tile GEMM inner loop, f32 inputs staged manually with swizzle.
__device__ __forceinline__ void gemm64_f32(
    const float* __restrict__ A, const float* __restrict__ Brow,
    int strideA, int strideB, int kbeg, int kend, int row0,
    bf16* As, bf16* Bs, f32x4 acc[4])
{
  const int t   = threadIdx.x;
  const int lane = t & 63, w = t >> 6, q = lane >> 4, c16 = lane & 15;
  const int sr  = t >> 3, lb = t & 7;

  for (int k0 = kbeg; k0 < kend; k0 += 64) {
    bf16x8 va[2], vb[2];
#pragma unroll
    for (int ch = 0; ch < 2; ch++) {
      int r    = ch * 32 + sr;
      int gcol = k0 + ((lb ^ (r & 7)) << 3);
      va[ch] = ld8f(A    + (size_t)(row0 + r) * strideA + gcol);
      vb[ch] = ld8f(Brow + (size_t)r * strideB + gcol);
    }
#pragma unroll
    for (int ch = 0; ch < 2; ch++) {
      *(bf16x8*)&As[ch * 2048 + t * 8] = va[ch];
      *(bf16x8*)&Bs[ch * 2048 + t * 8] = vb[ch];
    }
    __syncthreads();
#pragma unroll
    for (int kkb = 0; kkb < 8; kkb += 4) {
      int rb = w * 16 + c16;
      bf16x8 bfr = *(const bf16x8*)&Bs[rb * 64 + (((kkb + q) ^ (rb & 7)) << 3)];
#pragma unroll
      for (int i = 0; i < 4; i++) {
        int ra = i * 16 + c16;
        bf16x8 af = *(const bf16x8*)&As[ra * 64 + (((kkb + q) ^ (ra & 7)) << 3)];
        acc[i] = __builtin_amdgcn_mfma_f32_16x16x32_bf16(af, bfr, acc[i], 0, 0, 0);
      }
    }
    __syncthreads();
  }
}

// ---------------------------------------------------------------------------
// setup_k: role-switched mega-launch.
//   blocks [0,256)      : ugh GEMM  (u | gh from h0)  — latency-bound, first
//   blocks [256,384)    : xemb GEMM (split-K 4)
//   blocks [384,10624)  : f32->bf16 conversion (enc, W1, wi, fc1, fc2)
// ---------------------------------------------------------------------------
__global__ __launch_bounds__(256) void setup_k(
    const float* __restrict__ hidden, const float* __restrict__ W2,
    const float* __restrict__ wh, const float* __restrict__ W1_b,
    const float* __restrict__ W2_b, const float* __restrict__ gbh,
    const float* __restrict__ x, const float* __restrict__ o2e,
    const float* __restrict__ enc, const float* __restrict__ W1,
    const float* __restrict__ wi, const float* __restrict__ fc1w,
    const float* __restrict__ fc2w,
    bf16* __restrict__ enc_bf, bf16* __restrict__ W1_bf,
    bf16* __restrict__ wi_bf, bf16* __restrict__ fc1_bf,
    bf16* __restrict__ fc2_bf,
    bf16* __restrict__ u, bf16* __restrict__ gh, float* __restrict__ xe4)
{
  __shared__ __align__(16) bf16 As[64 * 64];
  __shared__ __align__(16) bf16 Bs[64 * 64];

  const int bid = blockIdx.x;
  const int t   = threadIdx.x;

  if (bid >= 384) {
    // -------- conversion role --------
    int i = bid - 384;
    const float* src; bf16* dst; int blk;
    if      (i < 8192) { src = enc;  dst = enc_bf; blk = i; }
    else if (i < 8448) { src = W1;   dst = W1_bf;  blk = i - 8192; }
    else if (i < 9600) { src = wi;   dst = wi_bf;  blk = i - 8448; }
    else if (i < 9728) { src = fc1w; dst = fc1_bf; blk = i - 9600; }
    else               { src = fc2w; dst = fc2_bf; blk = i - 9728; }
    const size_t base = (size_t)blk * 4096 + t * 16;
    const float* s = src + base;
    bf16* d = dst + base;
    *(bf16x8*)(d)     = ld8f(s);
    *(bf16x8*)(d + 8) = ld8f(s + 8);
    return;
  }

  const int lane = t & 63, w = t >> 6, q = lane >> 4, c16 = lane & 15;
  f32x4 acc[4] = {};

  if (bid < 256) {
    // -------- ugh role: cols [0,1024)->u (W2, +W1_b+W2_b); rest->gh --------
    const int row0 = (bid >> 6) * 64;
    const int col0 = (bid & 63) * 64;
    const bool isU = (col0 < 1024);
    const float* Brow = isU ? (W2 + (size_t)col0 * 1024)
                            : (wh + (size_t)(col0 - 1024) * 1024);
    gemm64_f32(hidden, Brow, 1024, 1024, 0, 1024, row0, As, Bs, acc);

    const int gc = col0 + w * 16 + c16;
    float bias = isU ? (W1_b[gc] + W2_b[gc]) : gbh[gc - 1024];
#pragma unroll
    for (int i = 0; i < 4; i++) {
      int gr0 = row0 + i * 16 + q * 4;
#pragma unroll
      for (int r = 0; r < 4; r++) {
        float v = acc[i][r] + bias;
        if (isU) u[(size_t)(gr0 + r) * 1024 + gc] = (bf16)v;
        else     gh[(size_t)(gr0 + r) * 3072 + (gc - 1024)] = (bf16)v;
      }
    }
  } else {
    // -------- xemb role: xe4[z] = x @ o2e^T over K slab z --------
    const int i3   = bid - 256;
    const int col0 = (i3 & 7) * 64;
    const int row0 = ((i3 >> 3) & 3) * 64;
    const int z    = i3 >> 5;
    gemm64_f32(x, o2e + (size_t)col0 * 4096, 4096, 4096,
               z * 1024, z * 1024 + 1024, row0, As, Bs, acc);

    const int gc = col0 + w * 16 + c16;
    float* out = xe4 + (size_t)z * 131072;
#pragma unroll
    for (int i = 0; i < 4; i++) {
      int gr0 = row0 + i * 16 + q * 4;
#pragma unroll
      for (int r = 0; r < 4; r++)
        out[(size_t)(gr0 + r) * 512 + gc] = acc[i][r];
    }
  }
}

// ---------------------------------------------------------------------------
// score_f2: e_part[bx][b*128+l] = sum_{d in 2 col-blocks} tanh(enc·W1+u)*Vw
// grid = (4, 256); block = 256 (4 waves, 128x128 tile per col-block pass).
// ---------------------------------------------------------------------------
__global__ __launch_bounds__(256) void score_f2(
    const bf16* __restrict__ A,    // enc_bf (32768 x 1024)
    const bf16* __restrict__ Bw,   // W1_bf (1024 x 1024)
    const bf16* __restrict__ u,    // (256 x 1024) bf16
    const float* __restrict__ Vw,  // (1024) f32
    float* __restrict__ e_part)    // (4 x 32768)
{
  __shared__ __align__(16) bf16 As[128 * 64];
  __shared__ __align__(16) bf16 Bs[128 * 64];
  __shared__ float s_part[2][128];

  const int t    = threadIdx.x;
  const int lane = t & 63;
  const int w    = t >> 6;
  const int wm   = w >> 1;
  const int wn   = w & 1;
  const int q    = lane >> 4;
  const int c16  = lane & 15;
  const int sr   = t >> 3;
  const int lb   = t & 7;

  const int row0 = blockIdx.y * 128;
  const int b    = blockIdx.y;

  float rowsum[4][4] = {};

#pragma unroll 1
  for (int cbp = 0; cbp < 2; cbp++) {
    const int col0 = (blockIdx.x * 2 + cbp) * 128;
    f32x4 acc[4][4] = {};

    for (int k0 = 0; k0 < 1024; k0 += 64) {
#pragma unroll
      for (int ch = 0; ch < 4; ch++) {
        int r    = ch * 32 + sr;
        int gcol = k0 + ((lb ^ (r & 7)) << 3);
        cp16(A  + (size_t)(row0 + r) * 1024 + gcol, &As[ch * 2048 + t * 8]);
        cp16(Bw + (size_t)(col0 + r) * 1024 + gcol, &Bs[ch * 2048 + t * 8]);
      }
      __syncthreads();
#pragma unroll
      for (int kkb = 0; kkb < 8; kkb += 4) {
        bf16x8 af[4], bfr[4];
#pragma unroll
        for (int i = 0; i < 4; i++) {
          int ra = wm * 64 + i * 16 + c16;
          af[i] = *(const bf16x8*)&As[ra * 64 + (((kkb + q) ^ (ra & 7)) << 3)];
        }
#pragma unroll
        for (int j = 0; j < 4; j++) {
          int rb = wn * 64 + j * 16 + c16;
          bfr[j] = *(const bf16x8*)&Bs[rb * 64 + (((kkb + q) ^ (rb & 7)) << 3)];
        }
#pragma unroll
        for (int i = 0; i < 4; i++)
#pragma unroll
          for (int j = 0; j < 4; j++)
            acc[i][j] = __builtin_amdgcn_mfma_f32_16x16x32_bf16(af[i], bfr[j], acc[i][j], 0, 0, 0);
      }
      __syncthreads();
    }

    // epilogue-accumulate this col-block into rowsum
#pragma unroll
    for (int i = 0; i < 4; i++) {
#pragma unroll
      for (int j = 0; j < 4; j++) {
        int gc   = col0 + wn * 64 + j * 16 + c16;
        float uc = (float)u[b * 1024 + gc];
        float vw = Vw[gc];
#pragma unroll
        for (int r = 0; r < 4; r++)
          rowsum[i][r] += fast_tanh(acc[i][j][r] + uc) * vw;
      }
    }
  }

  // cross-lane reduce over the 16 lanes sharing each row, then write
#pragma unroll
  for (int i = 0; i < 4; i++) {
#pragma unroll
    for (int r = 0; r < 4; r++) {
      float v = rowsum[i][r];
      v += __shfl_xor(v, 1);
      v += __shfl_xor(v, 2);
      v += __shfl_xor(v, 4);
      v += __shfl_xor(v, 8);
      if (c16 == 0) s_part[wn][wm * 64 + i * 16 + q * 4 + r] = v;
    }
  }
  __syncthreads();
  if (t < 128)
    e_part[(size_t)blockIdx.x * 32768 + row0 + t] = s_part[0][t] + s_part[1][t];
}

// ---------------------------------------------------------------------------
// softmax + context + x_emb pack. grid 256 (one per b).
// ---------------------------------------------------------------------------
__global__ __launch_bounds__(256) void softmax_f(
    const float* __restrict__ e_part, // (4, 32768)
    const bf16* __restrict__ enc,     // enc_bf
    const float* __restrict__ xe4,    // (4,256,512)
    const float* __restrict__ o2eb,   // (512)
    float* __restrict__ attn_out,     // -> d_out section 3
    bf16* __restrict__ rnn_in)        // (256,1536)
{
  const int b = blockIdx.x;
  const int t = threadIdx.x;
  __shared__ float se[128];

  if (t < 128) {
    float s = 0.0f;
#pragma unroll
    for (int cb = 0; cb < 4; cb++) s += e_part[(size_t)cb * 32768 + b * 128 + t];
    se[t] = s;
  }
  __syncthreads();

  float m = -1e30f;
  for (int l = 0; l < 128; l++) m = fmaxf(m, se[l]);
  float sum = 0.0f;
  for (int l = 0; l < 128; l++) sum += expf(se[l] - m);
  float inv = 1.0f / sum;
  __syncthreads();
  if (t < 128) {
    float p = expf(se[t] - m) * inv;
    attn_out[b * 128 + t] = p;
    se[t] = p;
  }
  __syncthreads();

  // context: thread t handles 4 contiguous k of 1024
  float a0 = 0, a1 = 0, a2 = 0, a3 = 0;
  const bf16* ep = enc + (size_t)b * L_ * ENC_ + t * 4;
  for (int l = 0; l < 128; l++) {
    float p = se[l];
    bf16x4 v = *(const bf16x4*)(ep + (size_t)l * ENC_);
    a0 += p * (float)v[0]; a1 += p * (float)v[1];
    a2 += p * (float)v[2]; a3 += p * (float)v[3];
  }
  bf16x4 o;
  o[0] = (bf16)a0; o[1] = (bf16)a1; o[2] = (bf16)a2; o[3] = (bf16)a3;
  *(bf16x4*)(rnn_in + (size_t)b * 1536 + t * 4) = o;

  // x_emb pack: rnn_in[b][1024+j] = sum_z xe4[z][b][j] + o2e_b[j]
#pragma unroll
  for (int jj = 0; jj < 2; jj++) {
    int j = jj * 256 + t;
    float v = o2eb[j];
#pragma unroll
    for (int z = 0; z < 4; z++) v += xe4[(size_t)z * 131072 + b * 512 + j];
    rnn_in[(size_t)b * 1536 + 1024 + j] = (bf16)v;
  }
}

// ---------------------------------------------------------------------------
// Generic bf16 skinny GEMM (global_load_lds + swizzle). 64x64 tile, BK=64.
// ---------------------------------------------------------------------------
template <int ACT, int OUTF32>
__global__ __launch_bounds__(256) void gemm_f(
    const bf16* __restrict__ A, const bf16* __restrict__ Bw,
    const float* __restrict__ bias1,
    void* __restrict__ C, int K, int out_ld)
{
  __shared__ __align__(16) bf16 As[64 * 64];
  __shared__ __align__(16) bf16 Bs[64 * 64];

  const int t    = threadIdx.x;
  const int lane = t & 63;
  const int w    = t >> 6;
  const int q    = lane >> 4;
  const int c16  = lane & 15;
  const int sr   = t >> 3;
  const int lb   = t & 7;
  const int row0 = blockIdx.y * 64;
  const int col0 = blockIdx.x * 64;

  f32x4 acc[4] = {};

  for (int k0 = 0; k0 < K; k0 += 64) {
#pragma unroll
    for (int ch = 0; ch < 2; ch++) {
      int r    = ch * 32 + sr;
      int gcol = k0 + ((lb ^ (r & 7)) << 3);
      cp16(A  + (size_t)(row0 + r) * K + gcol, &As[ch * 2048 + t * 8]);
      cp16(Bw + (size_t)(col0 + r) * K + gcol, &Bs[ch * 2048 + t * 8]);
    }
    __syncthreads();
#pragma unroll
    for (int kkb = 0; kkb < 8; kkb += 4) {
      int rb = w * 16 + c16;
      bf16x8 bfr = *(const bf16x8*)&Bs[rb * 64 + (((kkb + q) ^ (rb & 7)) << 3)];
#pragma unroll
      for (int i = 0; i < 4; i++) {
        int ra = i * 16 + c16;
        bf16x8 af = *(const bf16x8*)&As[ra * 64 + (((kkb + q) ^ (ra & 7)) << 3)];
        acc[i] = __builtin_amdgcn_mfma_f32_16x16x32_bf16(af, bfr, acc[i], 0, 0, 0);
      }
    }
    __syncthreads();
  }

  const int gc = col0 + w * 16 + c16;
  float bias = bias1[gc];
#pragma unroll
  for (int i = 0; i < 4; i++) {
    int gr0 = row0 + i * 16 + q * 4;
#pragma unroll
    for (int r = 0; r < 4; r++) {
      float v = acc[i][r] + bias;
      if (ACT == 1) v = fast_tanh(v);
      size_t off = (size_t)(gr0 + r) * out_ld + gc;
      if (OUTF32) ((float*)C)[off] = v;
      else        ((bf16*)C)[off] = (bf16)v;
    }
  }
}

// ---------------------------------------------------------------------------
// GRU gates. 262144 threads. h0 f32 external.
// ---------------------------------------------------------------------------
__global__ __launch_bounds__(256) void gru_f(
    const bf16* __restrict__ gi, const bf16* __restrict__ gh,
    const float* __restrict__ h0,
    float* __restrict__ hnew_out, bf16* __restrict__ hnew_i)
{
  int idx = blockIdx.x * 256 + threadIdx.x;
  int b = idx >> 10, d = idx & 1023;
  const bf16* gib = gi + b * 3072;
  const bf16* ghb = gh + b * 3072;
  float ir = (float)gib[d], iz = (float)gib[1024 + d], in = (float)gib[2048 + d];
  float hr = (float)ghb[d], hz = (float)ghb[1024 + d], hn = (float)ghb[2048 + d];
  float r = fast_sigmoid(ir + hr);
  float z = fast_sigmoid(iz + hz);
  float n = fast_tanh(in + r * hn);
  float h = (1.0f - z) * n + z * h0[idx];
  hnew_out[idx] = h;
  hnew_i[idx]   = (bf16)h;
}

// ---------------------------------------------------------------------------
extern "C" void kernel_launch(void* const* d_in, const int* in_sizes, int n_in,
                              void* d_out, int out_size, void* d_ws, size_t ws_size,
                              hipStream_t stream) {
  const float* x      = (const float*)d_in[0];
  const float* hidden = (const float*)d_in[1];
  const float* enc    = (const float*)d_in[2];
  const float* W1_w   = (const float*)d_in[3];
  const float* W1_b   = (const float*)d_in[4];
  const float* W2_w   = (const float*)d_in[5];
  const float* W2_b   = (const float*)d_in[6];
  const float* V_w    = (const float*)d_in[7];
  // d_in[8] = V_b : softmax-invariant, unused
  const float* o2e_w  = (const float*)d_in[9];
  const float* o2e_b  = (const float*)d_in[10];
  const float* gru_wi = (const float*)d_in[11];
  const float* gru_wh = (const float*)d_in[12];
  const float* gru_bi = (const float*)d_in[13];
  const float* gru_bh = (const float*)d_in[14];
  const float* fc1_w  = (const float*)d_in[15];
  const float* fc1_b  = (const float*)d_in[16];
  const float* fc2_w  = (const float*)d_in[17];
  const float* fc2_b  = (const float*)d_in[18];

  float* out_main = (float*)d_out;                      // (256,4096)
  float* out_h    = out_main + (size_t)B_ * V_;         // (256,1024)
  float* out_attn = out_h + (size_t)B_ * DEC_;          // (256,128)

  // ws layout (bytes); NEED ~88 MB (ws_size >= ~103 MB measured in R5)
  char* ws = (char*)d_ws;
  bf16*  enc_bf  = (bf16*)(ws);                    // 64 MB
  bf16*  W1_bf   = (bf16*)(ws + 64 * MB_);         // 2 MB
  bf16*  wi_bf   = (bf16*)(ws + 66 * MB_);         // 9 MB
  bf16*  fc1_bf  = (bf16*)(ws + 75 * MB_);         // 1 MB
  bf16*  fc2_bf  = (bf16*)(ws + 76 * MB_);         // 4 MB
  bf16*  u_bf    = (bf16*)(ws + 80 * MB_);         // 512 KB
  bf16*  gh_bf   = (bf16*)(ws + 80 * MB_ + 524288);      // 1.5 MB
  float* e_part  = (float*)(ws + 82 * MB_);              // 512 KB
  bf16*  gi_bf   = (bf16*)(ws + 82 * MB_ + 524288);      // 1.5 MB
  bf16*  rnn_in  = (bf16*)(ws + 84 * MB_);               // 768 KB
  bf16*  tbuf    = (bf16*)(ws + 84 * MB_ + 786432);      // 256 KB
  bf16*  hnew_bf = (bf16*)(ws + 85 * MB_);               // 512 KB
  float* xe4     = (float*)(ws + 85 * MB_ + 524288);     // 2 MB

  // 1. setup: ugh + xemb GEMMs (blocks 0..383) overlapped with conversions
  setup_k<<<10624, 256, 0, stream>>>(
      hidden, W2_w, gru_wh, W1_b, W2_b, gru_bh, x, o2e_w,
      enc, W1_w, gru_wi, fc1_w, fc2_w,
      enc_bf, W1_bf, wi_bf, fc1_bf, fc2_bf, u_bf, gh_bf, xe4);

  // 2. score GEMM (2 col-blocks per block) -> e_part
  score_f2<<<dim3(4, 256), 256, 0, stream>>>(enc_bf, W1_bf, u_bf, V_w, e_part);

  // 3. softmax + context + x_emb pack
  softmax_f<<<B_, 256, 0, stream>>>(e_part, enc_bf, xe4, o2e_b, out_attn, rnn_in);

  // 4. gi = rnn_in @ wi^T + gru_bi (256x3072, K=1536)
  gemm_f<0, 0><<<dim3(48, 4), 256, 0, stream>>>(rnn_in, wi_bf, gru_bi, gi_bf, 1536, 3072);

  // 5. GRU gates -> h_new
  gru_f<<<(B_ * DEC_) / 256, 256, 0, stream>>>(gi_bf, gh_bf, hidden, out_h, hnew_bf);

  // 6. t = tanh(h_new @ fc1^T + fc1_b) (256x512, K=1024)
  gemm_f<1, 0><<<dim3(8, 4), 256, 0, stream>>>(hnew_bf, fc1_bf, fc1_b, tbuf, 1024, 512);

  // 7. out = t @ fc2^T + fc2_b (256x4096, K=512, f32 out)
  gemm_f<0, 1><<<dim3(64, 4), 256, 0, stream>>>(tbuf, fc2_bf, fc2_b, out_main, 512, 4096);
}